// Round 4
// baseline (682.907 us; speedup 1.0000x reference)
//
#include <hip/hip_runtime.h>
#include <math.h>

#define CH 96
#define DIN 192
#define NSTATE 16
#define DTRc 6
#define NPROJ 38
#define Bn 2
#define Ln 16384
#define NCc 1024
#define CLc 16
#define SLAB (Bn*DIN*NSTATE)   /* 6144 floats per ci-slab */
#define LT 64
#define LP 32

typedef __attribute__((ext_vector_type(8))) short bf16x8;
typedef __attribute__((ext_vector_type(4))) float f32x4;

__device__ __forceinline__ float sigf(float x){ return 1.f/(1.f+__expf(-x)); }
__device__ __forceinline__ unsigned short f2bf(float f){
  unsigned int u = __float_as_uint(f);
  unsigned int r = (u + 0x7fffu + ((u>>16)&1u)) >> 16;
  return (unsigned short)r;
}

// ---------------- LayerNorm: x (B,C,L) -> xn bf16 (B,L,C) ----------------
__global__ __launch_bounds__(256) void k_ln(const float* __restrict__ x,
    const float* __restrict__ g, const float* __restrict__ bb,
    unsigned short* __restrict__ xnb){
  __shared__ float tile[CH*65];
  __shared__ float ps[4*64], ps2[4*64];
  __shared__ float mus[64], rss[64];
  int b = blockIdx.x / (Ln/LT);
  int l0 = (blockIdx.x % (Ln/LT)) * LT;
  int t = threadIdx.x;
  for(int i=t;i<CH*LT;i+=256){ int c=i/LT, j=i%LT; tile[c*65+j] = x[(b*CH+c)*Ln + l0 + j]; }
  __syncthreads();
  { int j = t & 63, part = t >> 6;
    float s=0.f, s2=0.f;
    #pragma unroll
    for(int c=part*24; c<part*24+24; ++c){ float v=tile[c*65+j]; s+=v; s2+=v*v; }
    ps[part*64+j]=s; ps2[part*64+j]=s2; }
  __syncthreads();
  if(t<64){
    float s=0.f,s2=0.f;
    #pragma unroll
    for(int p=0;p<4;p++){ s+=ps[p*64+t]; s2+=ps2[p*64+t]; }
    float mu = s*(1.f/CH);
    float var = s2*(1.f/CH) - mu*mu;
    mus[t]=mu; rss[t]=rsqrtf(var+1e-5f);
  }
  __syncthreads();
  for(int i=t;i<CH*LT;i+=256){ int j=i/CH, c=i%CH;
    float v=(tile[c*65+j]-mus[j])*rss[j]*g[c]+bb[c];
    xnb[(size_t)(b*Ln+l0+j)*CH + c]=f2bf(v); }
}

// ---------------- weight cast f32 -> bf16 ----------------
__global__ __launch_bounds__(256) void k_wcast(const float* __restrict__ w,
    unsigned short* __restrict__ wb, int n){
  int i = blockIdx.x*256 + threadIdx.x;
  if(i<n) wb[i]=f2bf(w[i]);
}

// ---------------- In-proj via bf16 MFMA: rows x 384, K=96 ----------------
// grid = Bn*Ln/64 blocks, 256 thr = 4 waves x 16 rows. A,B frags loaded
// directly from row-major global (16B contiguous per lane). No LDS.
__global__ __launch_bounds__(256) void k_inproj(const unsigned short* __restrict__ xnb,
    const unsigned short* __restrict__ wbf, float* __restrict__ xi,
    float* __restrict__ zs, int dir){
  int wave = threadIdx.x >> 6;
  int lane = threadIdx.x & 63;
  int row0 = blockIdx.x*64 + wave*16;       // output row base (b*Ln+p)
  int b  = row0 >> 14;
  int p0 = row0 & (Ln-1);
  int rlo = lane & 15, khi = lane >> 4;     // khi = k-slice 0..3
  int p_in = dir ? (Ln-1-(p0+rlo)) : (p0+rlo);
  const bf16x8* Ap = (const bf16x8*)(xnb + ((size_t)b*Ln + p_in)*CH);
  bf16x8 a0 = Ap[khi];        // k = 0..31
  bf16x8 a1 = Ap[4+khi];      // k = 32..63
  bf16x8 a2 = Ap[8+khi];      // k = 64..95
  f32x4 acc[24];
  #pragma unroll
  for(int nt=0;nt<24;nt++){
    const bf16x8* Bp = (const bf16x8*)(wbf + (size_t)(nt*16+rlo)*CH);
    f32x4 c = {0.f,0.f,0.f,0.f};
    c = __builtin_amdgcn_mfma_f32_16x16x32_bf16(a0, Bp[khi],   c, 0,0,0);
    c = __builtin_amdgcn_mfma_f32_16x16x32_bf16(a1, Bp[4+khi], c, 0,0,0);
    c = __builtin_amdgcn_mfma_f32_16x16x32_bf16(a2, Bp[8+khi], c, 0,0,0);
    acc[nt]=c;
  }
  #pragma unroll
  for(int nt=0;nt<24;nt++){
    int n = nt*16 + rlo;          // D col = lane&15
    #pragma unroll
    for(int j=0;j<4;j++){
      int p = p0 + khi*4 + j;     // D row = (lane>>4)*4+reg
      size_t rowo = ((size_t)b*Ln + p)*DIN;
      float v = acc[nt][j];
      if(nt<12) xi[rowo + n] = v;
      else      zs[rowo + n - DIN] = v*sigf(v);
    }
  }
}

// ---------------- causal depthwise conv(4) + bias + silu ----------------
__global__ __launch_bounds__(256) void k_conv(const float* __restrict__ xi,
    const float* __restrict__ cw, const float* __restrict__ cb, float* __restrict__ xc){
  int i = blockIdx.x*256 + threadIdx.x;
  if(i >= Bn*Ln*DIN) return;
  int d = i % DIN; int p = (i/DIN) % Ln; int b = i/(DIN*Ln);
  float acc = cb[d];
  #pragma unroll
  for(int k=0;k<4;k++){ int q = p-3+k; if(q>=0) acc += xi[(size_t)(b*Ln+q)*DIN+d]*cw[d*4+k]; }
  xc[i] = acc * sigf(acc);
}

// ---------------- x-proj (192->38) + delta (6->192, softplus) ----------------
__global__ __launch_bounds__(256) void k_xproj(const float* __restrict__ xc,
    const float* __restrict__ xpw, const float* __restrict__ dtw, const float* __restrict__ dtb,
    float* __restrict__ delta, float* __restrict__ Bm, float* __restrict__ Cm){
  __shared__ float w_s[40*196];
  __shared__ float dtw_s[DIN*DTRc];
  __shared__ float dbl[LP*40];
  int b  = blockIdx.x / (Ln/LP);
  int l0 = (blockIdx.x % (Ln/LP)) * LP;
  int t = threadIdx.x;
  for(int i=t;i<NPROJ*DIN;i+=256){ int o=i/DIN,c=i%DIN; w_s[o*196+c]=xpw[i]; }
  for(int i=t;i<DIN*DTRc;i+=256) dtw_s[i]=dtw[i];
  __syncthreads();
  { int og = t & 7, j = t >> 3;
    const float* xr = xc + (size_t)(b*Ln+l0+j)*DIN;
    float acc[5];
    #pragma unroll
    for(int k=0;k<5;k++) acc[k]=0.f;
    for(int c=0;c<DIN;c+=4){
      float4 xv = *(const float4*)&xr[c];
      #pragma unroll
      for(int k=0;k<5;k++){
        float4 wv = *(const float4*)&w_s[(og+8*k)*196+c];
        acc[k] += xv.x*wv.x + xv.y*wv.y + xv.z*wv.z + xv.w*wv.w;
      }
    }
    #pragma unroll
    for(int k=0;k<5;k++){ int o=og+8*k; if(o<NPROJ) dbl[j*40+o]=acc[k]; }
  }
  __syncthreads();
  for(int i=t;i<LP*DIN;i+=256){ int j=i/DIN, d=i%DIN;
    float a=dtb[d];
    #pragma unroll
    for(int r=0;r<DTRc;r++) a += dbl[j*40+r]*dtw_s[d*DTRc+r];
    float sp = (a>20.f)? a : log1pf(__expf(a));
    delta[(size_t)(b*Ln+l0+j)*DIN+d]=sp;
  }
  for(int i=t;i<LP*32;i+=256){ int j=i/32,qq=i%32;
    float v=dbl[j*40+DTRc+qq];
    if(qq<NSTATE) Bm[(size_t)(b*Ln+l0+j)*NSTATE+qq]=v;
    else Cm[(size_t)(b*Ln+l0+j)*NSTATE+qq-NSTATE]=v;
  }
}

// ---------------- scan pass 1: per-chunk (S=sum delta, B_seg) ----------------
__global__ __launch_bounds__(192) void k_scan1(const float* __restrict__ delta,
    const float* __restrict__ xc, const float* __restrict__ Bm,
    const float* __restrict__ A_log, float* __restrict__ Ssg, float* __restrict__ Bsg){
  int b = blockIdx.x / NCc; int ci = blockIdx.x % NCc; int d = threadIdx.x;
  __shared__ float bm[CLc*NSTATE];
  for(int i=d;i<CLc*NSTATE;i+=192) bm[i]=Bm[(size_t)(b*Ln+ci*CLc)*NSTATE+i];
  float kA[NSTATE];
  { const float4* al=(const float4*)&A_log[d*NSTATE];
    #pragma unroll
    for(int v4=0;v4<4;v4++){ float4 a=al[v4];
      kA[v4*4+0]=-__expf(a.x)*1.4426950408889634f;
      kA[v4*4+1]=-__expf(a.y)*1.4426950408889634f;
      kA[v4*4+2]=-__expf(a.z)*1.4426950408889634f;
      kA[v4*4+3]=-__expf(a.w)*1.4426950408889634f; } }
  float h[NSTATE];
  #pragma unroll
  for(int n=0;n<NSTATE;n++) h[n]=0.f;
  float S=0.f;
  __syncthreads();
  const float* dp = delta + ((size_t)b*Ln+ci*CLc)*DIN + d;
  const float* xp = xc    + ((size_t)b*Ln+ci*CLc)*DIN + d;
  for(int ll=0;ll<CLc;ll++){
    float dl=dp[ll*DIN];
    float xv=xp[ll*DIN];
    float bx=dl*xv;
    S+=dl;
    float bv[NSTATE];
    { const float4* qq=(const float4*)&bm[ll*NSTATE];
      #pragma unroll
      for(int v4=0;v4<4;v4++){ float4 a=qq[v4]; bv[v4*4]=a.x; bv[v4*4+1]=a.y; bv[v4*4+2]=a.z; bv[v4*4+3]=a.w; } }
    #pragma unroll
    for(int n=0;n<NSTATE;n++){
      float a=exp2f(kA[n]*dl);
      h[n]=fmaf(a,h[n],bx*bv[n]);
    }
  }
  Ssg[(size_t)ci*(Bn*DIN) + b*DIN + d] = S;
  size_t wb = (((size_t)ci*Bn + b)*DIN + d)*NSTATE;
  #pragma unroll
  for(int v4=0;v4<4;v4++){
    float4 bv4;
    bv4.x=h[v4*4+0]; bv4.y=h[v4*4+1]; bv4.z=h[v4*4+2]; bv4.w=h[v4*4+3];
    *(float4*)&Bsg[wb+v4*4]=bv4;
  }
}

// ---------------- scan pass 2: sequential chunk combine, in-place h_in into Bsg ----------------
// grid = Bn*(DIN/16) = 24 blocks; 256 threads = 16 d x 16 n.
__global__ __launch_bounds__(256) void k_scan2(const float* __restrict__ Ssg,
    float* __restrict__ Bsg, const float* __restrict__ A_log){
  int t = threadIdx.x;
  int dg = blockIdx.x % (DIN/16);
  int b  = blockIdx.x / (DIN/16);
  int d = dg*16 + (t>>4);
  int n = t & 15;
  float kA = -__expf(A_log[d*NSTATE+n])*1.4426950408889634f;
  size_t off = ((size_t)b*DIN + d)*NSTATE + n;
  size_t soff = (size_t)b*DIN + d;
  float h=0.f;
  for(int ci=0; ci<NCc; ++ci){
    float s = Ssg[(size_t)ci*(Bn*DIN) + soff];
    size_t idx = (size_t)ci*SLAB + off;
    float bb=Bsg[idx];
    Bsg[idx]=h;
    h = fmaf(exp2f(kA*s),h,bb);
  }
}

// ---------------- scan pass 3: replay from h_in, emit y*silu(z) ----------------
__global__ __launch_bounds__(192) void k_scan3(const float* __restrict__ delta,
    const float* __restrict__ xc, const float* __restrict__ Bm, const float* __restrict__ Cm,
    const float* __restrict__ Hseg, const float* __restrict__ A_log, const float* __restrict__ Dp,
    const float* __restrict__ zs, float* __restrict__ yacc, int dir){
  int b=blockIdx.x/NCc; int ci=blockIdx.x%NCc; int d=threadIdx.x;
  __shared__ float bm[CLc*NSTATE], cm[CLc*NSTATE];
  for(int i=d;i<CLc*NSTATE;i+=192){
    bm[i]=Bm[(size_t)(b*Ln+ci*CLc)*NSTATE+i];
    cm[i]=Cm[(size_t)(b*Ln+ci*CLc)*NSTATE+i];
  }
  float kA[NSTATE];
  { const float4* al=(const float4*)&A_log[d*NSTATE];
    #pragma unroll
    for(int v4=0;v4<4;v4++){ float4 a=al[v4];
      kA[v4*4+0]=-__expf(a.x)*1.4426950408889634f;
      kA[v4*4+1]=-__expf(a.y)*1.4426950408889634f;
      kA[v4*4+2]=-__expf(a.z)*1.4426950408889634f;
      kA[v4*4+3]=-__expf(a.w)*1.4426950408889634f; } }
  float Dd=Dp[d];
  float h[NSTATE];
  { size_t rb = (((size_t)ci*Bn + b)*DIN + d)*NSTATE;
    const float4* hp=(const float4*)&Hseg[rb];
    #pragma unroll
    for(int v4=0;v4<4;v4++){ float4 a=hp[v4]; h[v4*4]=a.x; h[v4*4+1]=a.y; h[v4*4+2]=a.z; h[v4*4+3]=a.w; } }
  __syncthreads();
  const float* dp = delta + ((size_t)b*Ln+ci*CLc)*DIN + d;
  const float* xp = xc    + ((size_t)b*Ln+ci*CLc)*DIN + d;
  const float* zp = zs    + ((size_t)b*Ln+ci*CLc)*DIN + d;
  for(int ll=0;ll<CLc;ll++){
    float dl=dp[ll*DIN];
    float xv=xp[ll*DIN];
    float zv=zp[ll*DIN];
    float bx=dl*xv;
    float bv[NSTATE], cv[NSTATE];
    { const float4* qq=(const float4*)&bm[ll*NSTATE];
      const float4* rr=(const float4*)&cm[ll*NSTATE];
      #pragma unroll
      for(int v4=0;v4<4;v4++){ float4 a=qq[v4]; bv[v4*4]=a.x; bv[v4*4+1]=a.y; bv[v4*4+2]=a.z; bv[v4*4+3]=a.w;
                               float4 c=rr[v4]; cv[v4*4]=c.x; cv[v4*4+1]=c.y; cv[v4*4+2]=c.z; cv[v4*4+3]=c.w; } }
    float y=0.f;
    #pragma unroll
    for(int n=0;n<NSTATE;n++){
      float a=exp2f(kA[n]*dl);
      h[n]=fmaf(a,h[n],bx*bv[n]);
      y=fmaf(h[n],cv[n],y);
    }
    y=fmaf(xv,Dd,y);
    float o=y*zv;
    int l=ci*CLc+ll;
    int p = dir? (Ln-1-l) : l;
    float* yp=&yacc[(size_t)(b*Ln+p)*DIN+d];
    if(dir==0) *yp=o; else *yp+=o;
  }
}

// ---------------- out-proj GEMM (192->96) + residual, write (B,C,L) ----------------
__global__ __launch_bounds__(256) void k_out(const float* __restrict__ x,
    const float* __restrict__ ya, const float* __restrict__ ow, float* __restrict__ out){
  __shared__ float yt[LT*196];
  int b=blockIdx.x/(Ln/LT); int l0=(blockIdx.x%(Ln/LT))*LT; int t=threadIdx.x;
  for(int i=t;i<LT*DIN;i+=256){ int j=i/DIN,c=i%DIN; yt[j*196+c]=ya[(size_t)(b*Ln+l0+j)*DIN+c]; }
  __syncthreads();
  int tp=t&15, tc=t>>4;
  float acc[6][4];
  #pragma unroll
  for(int j=0;j<6;j++)
    #pragma unroll
    for(int k=0;k<4;k++) acc[j][k]=0.f;
  for(int dd=0; dd<DIN; dd+=4){
    float4 yv[4];
    #pragma unroll
    for(int k=0;k<4;k++) yv[k]=*(const float4*)&yt[(tp+16*k)*196+dd];
    #pragma unroll
    for(int j=0;j<6;j++){
      float4 wv=*(const float4*)&ow[(tc+16*j)*DIN+dd];
      #pragma unroll
      for(int k=0;k<4;k++)
        acc[j][k]+=yv[k].x*wv.x+yv[k].y*wv.y+yv[k].z*wv.z+yv[k].w*wv.w;
    }
  }
  #pragma unroll
  for(int j=0;j<6;j++){ int c=tc+16*j;
    #pragma unroll
    for(int k=0;k<4;k++){ int p=l0+tp+16*k;
      int o=(b*CH+c)*Ln+p;
      out[o]=x[o]+acc[j][k]; } }
}

extern "C" void kernel_launch(void* const* d_in, const int* in_sizes, int n_in,
                              void* d_out, int out_size, void* d_ws, size_t ws_size,
                              hipStream_t stream){
  const float* x =(const float*)d_in[0];
  const float* g =(const float*)d_in[1];
  const float* be=(const float*)d_in[2];
  const float* ow=(const float*)d_in[3];
  const float* P[2][8];
  for(int dir=0;dir<2;dir++) for(int k=0;k<8;k++) P[dir][k]=(const float*)d_in[4+dir*8+k];
  float* ws=(float*)d_ws;
  size_t o=0;
  unsigned short* xnb = (unsigned short*)(ws+o); o+=(size_t)Bn*Ln*CH/2;   // bf16
  unsigned short* wbf = (unsigned short*)(ws+o); o+=(size_t)(2*DIN*CH+2)/2;
  float* xi  = ws+o; o+=(size_t)Bn*Ln*DIN;   // hosts Bsg during scans (xi dead then)
  float* zsb = ws+o; o+=(size_t)Bn*Ln*DIN;
  float* xcb = ws+o; o+=(size_t)Bn*Ln*DIN;
  float* de  = ws+o; o+=(size_t)Bn*Ln*DIN;
  float* Bmb = ws+o; o+=(size_t)Bn*Ln*NSTATE;
  float* Cmb = ws+o; o+=(size_t)Bn*Ln*NSTATE;
  float* ya  = ws+o; o+=(size_t)Bn*Ln*DIN;
  float* Ssg = ws+o; o+=(size_t)NCc*Bn*DIN;
  float* Bsg = xi;                            // SLAB*NCc = 6,291,456 = |xi|
  float* outp=(float*)d_out;

  k_ln<<<dim3(Bn*(Ln/LT)),dim3(256),0,stream>>>(x,g,be,xnb);
  for(int dir=0;dir<2;dir++){
    const float* in_w=P[dir][0]; const float* cw=P[dir][1]; const float* cb=P[dir][2];
    const float* xpw =P[dir][3]; const float* dtw=P[dir][4]; const float* dtb=P[dir][5];
    const float* Al  =P[dir][6]; const float* Dp =P[dir][7];
    k_wcast <<<dim3((2*DIN*CH+255)/256),dim3(256),0,stream>>>(in_w,wbf,2*DIN*CH);
    k_inproj<<<dim3(Bn*Ln/64),dim3(256),0,stream>>>(xnb,wbf,xi,zsb,dir);
    k_conv  <<<dim3((Bn*Ln*DIN+255)/256),dim3(256),0,stream>>>(xi,cw,cb,xcb);
    k_xproj <<<dim3(Bn*(Ln/LP)),dim3(256),0,stream>>>(xcb,xpw,dtw,dtb,de,Bmb,Cmb);
    k_scan1 <<<dim3(Bn*NCc),dim3(192),0,stream>>>(de,xcb,Bmb,Al,Ssg,Bsg);
    k_scan2 <<<dim3(Bn*(DIN/16)),dim3(256),0,stream>>>(Ssg,Bsg,Al);
    k_scan3 <<<dim3(Bn*NCc),dim3(192),0,stream>>>(de,xcb,Bmb,Cmb,Bsg,Al,Dp,zsb,ya,dir);
  }
  k_out<<<dim3(Bn*(Ln/LT)),dim3(256),0,stream>>>(x,ya,ow,outp);
}

// Round 5
// 452.615 us; speedup vs baseline: 1.5088x; 1.5088x over previous
//
#include <hip/hip_runtime.h>
#include <math.h>

#define CH 96
#define DIN 192
#define NSTATE 16
#define DTRc 6
#define NPROJ 38
#define Bn 2
#define Ln 16384
#define NCc 1024
#define CLc 16
#define SLAB (Bn*DIN*NSTATE)   /* 6144 floats per ci-slab == number of scan lines */
#define NG 16
#define GC (NCc/NG)            /* 64 chunks per group */
#define LT 64
#define LP 32

typedef __attribute__((ext_vector_type(8))) short bf16x8;
typedef __attribute__((ext_vector_type(4))) float f32x4;

__device__ __forceinline__ float sigf(float x){ return 1.f/(1.f+__expf(-x)); }
__device__ __forceinline__ unsigned short f2bf(float f){
  unsigned int u = __float_as_uint(f);
  unsigned int r = (u + 0x7fffu + ((u>>16)&1u)) >> 16;
  return (unsigned short)r;
}

// ---------------- LayerNorm: x (B,C,L) -> xn bf16 (B,L,C) ----------------
__global__ __launch_bounds__(256) void k_ln(const float* __restrict__ x,
    const float* __restrict__ g, const float* __restrict__ bb,
    unsigned short* __restrict__ xnb){
  __shared__ float tile[CH*65];
  __shared__ float ps[4*64], ps2[4*64];
  __shared__ float mus[64], rss[64];
  int b = blockIdx.x / (Ln/LT);
  int l0 = (blockIdx.x % (Ln/LT)) * LT;
  int t = threadIdx.x;
  for(int i=t;i<CH*LT;i+=256){ int c=i/LT, j=i%LT; tile[c*65+j] = x[(b*CH+c)*Ln + l0 + j]; }
  __syncthreads();
  { int j = t & 63, part = t >> 6;
    float s=0.f, s2=0.f;
    #pragma unroll
    for(int c=part*24; c<part*24+24; ++c){ float v=tile[c*65+j]; s+=v; s2+=v*v; }
    ps[part*64+j]=s; ps2[part*64+j]=s2; }
  __syncthreads();
  if(t<64){
    float s=0.f,s2=0.f;
    #pragma unroll
    for(int p=0;p<4;p++){ s+=ps[p*64+t]; s2+=ps2[p*64+t]; }
    float mu = s*(1.f/CH);
    float var = s2*(1.f/CH) - mu*mu;
    mus[t]=mu; rss[t]=rsqrtf(var+1e-5f);
  }
  __syncthreads();
  for(int i=t;i<CH*LT;i+=256){ int j=i/CH, c=i%CH;
    float v=(tile[c*65+j]-mus[j])*rss[j]*g[c]+bb[c];
    xnb[(size_t)(b*Ln+l0+j)*CH + c]=f2bf(v); }
}

// ---------------- weight cast f32 -> bf16 ----------------
__global__ __launch_bounds__(256) void k_wcast(const float* __restrict__ w,
    unsigned short* __restrict__ wb, int n){
  int i = blockIdx.x*256 + threadIdx.x;
  if(i<n) wb[i]=f2bf(w[i]);
}

// ---------------- In-proj via bf16 MFMA: rows x 384, K=96 ----------------
__global__ __launch_bounds__(256) void k_inproj(const unsigned short* __restrict__ xnb,
    const unsigned short* __restrict__ wbf, float* __restrict__ xi,
    float* __restrict__ zs, int dir){
  int wave = threadIdx.x >> 6;
  int lane = threadIdx.x & 63;
  int row0 = blockIdx.x*64 + wave*16;
  int b  = row0 >> 14;
  int p0 = row0 & (Ln-1);
  int rlo = lane & 15, khi = lane >> 4;
  int p_in = dir ? (Ln-1-(p0+rlo)) : (p0+rlo);
  const bf16x8* Ap = (const bf16x8*)(xnb + ((size_t)b*Ln + p_in)*CH);
  bf16x8 a0 = Ap[khi];
  bf16x8 a1 = Ap[4+khi];
  bf16x8 a2 = Ap[8+khi];
  f32x4 acc[24];
  #pragma unroll
  for(int nt=0;nt<24;nt++){
    const bf16x8* Bp = (const bf16x8*)(wbf + (size_t)(nt*16+rlo)*CH);
    f32x4 c = {0.f,0.f,0.f,0.f};
    c = __builtin_amdgcn_mfma_f32_16x16x32_bf16(a0, Bp[khi],   c, 0,0,0);
    c = __builtin_amdgcn_mfma_f32_16x16x32_bf16(a1, Bp[4+khi], c, 0,0,0);
    c = __builtin_amdgcn_mfma_f32_16x16x32_bf16(a2, Bp[8+khi], c, 0,0,0);
    acc[nt]=c;
  }
  #pragma unroll
  for(int nt=0;nt<24;nt++){
    int n = nt*16 + rlo;
    #pragma unroll
    for(int j=0;j<4;j++){
      int p = p0 + khi*4 + j;
      size_t rowo = ((size_t)b*Ln + p)*DIN;
      float v = acc[nt][j];
      if(nt<12) xi[rowo + n] = v;
      else      zs[rowo + n - DIN] = v*sigf(v);
    }
  }
}

// ---------------- causal depthwise conv(4) + bias + silu ----------------
__global__ __launch_bounds__(256) void k_conv(const float* __restrict__ xi,
    const float* __restrict__ cw, const float* __restrict__ cb, float* __restrict__ xc){
  int i = blockIdx.x*256 + threadIdx.x;
  if(i >= Bn*Ln*DIN) return;
  int d = i % DIN; int p = (i/DIN) % Ln; int b = i/(DIN*Ln);
  float acc = cb[d];
  #pragma unroll
  for(int k=0;k<4;k++){ int q = p-3+k; if(q>=0) acc += xi[(size_t)(b*Ln+q)*DIN+d]*cw[d*4+k]; }
  xc[i] = acc * sigf(acc);
}

// ---------------- x-proj (192->38) + delta (6->192, softplus) ----------------
__global__ __launch_bounds__(256) void k_xproj(const float* __restrict__ xc,
    const float* __restrict__ xpw, const float* __restrict__ dtw, const float* __restrict__ dtb,
    float* __restrict__ delta, float* __restrict__ Bm, float* __restrict__ Cm){
  __shared__ float w_s[40*196];
  __shared__ float dtw_s[DIN*DTRc];
  __shared__ float dbl[LP*40];
  int b  = blockIdx.x / (Ln/LP);
  int l0 = (blockIdx.x % (Ln/LP)) * LP;
  int t = threadIdx.x;
  for(int i=t;i<NPROJ*DIN;i+=256){ int o=i/DIN,c=i%DIN; w_s[o*196+c]=xpw[i]; }
  for(int i=t;i<DIN*DTRc;i+=256) dtw_s[i]=dtw[i];
  __syncthreads();
  { int og = t & 7, j = t >> 3;
    const float* xr = xc + (size_t)(b*Ln+l0+j)*DIN;
    float acc[5];
    #pragma unroll
    for(int k=0;k<5;k++) acc[k]=0.f;
    for(int c=0;c<DIN;c+=4){
      float4 xv = *(const float4*)&xr[c];
      #pragma unroll
      for(int k=0;k<5;k++){
        float4 wv = *(const float4*)&w_s[(og+8*k)*196+c];
        acc[k] += xv.x*wv.x + xv.y*wv.y + xv.z*wv.z + xv.w*wv.w;
      }
    }
    #pragma unroll
    for(int k=0;k<5;k++){ int o=og+8*k; if(o<NPROJ) dbl[j*40+o]=acc[k]; }
  }
  __syncthreads();
  for(int i=t;i<LP*DIN;i+=256){ int j=i/DIN, d=i%DIN;
    float a=dtb[d];
    #pragma unroll
    for(int r=0;r<DTRc;r++) a += dbl[j*40+r]*dtw_s[d*DTRc+r];
    float sp = (a>20.f)? a : log1pf(__expf(a));
    delta[(size_t)(b*Ln+l0+j)*DIN+d]=sp;
  }
  for(int i=t;i<LP*32;i+=256){ int j=i/32,qq=i%32;
    float v=dbl[j*40+DTRc+qq];
    if(qq<NSTATE) Bm[(size_t)(b*Ln+l0+j)*NSTATE+qq]=v;
    else Cm[(size_t)(b*Ln+l0+j)*NSTATE+qq-NSTATE]=v;
  }
}

// ---------------- scan pass 1: per-chunk (S=sum delta, B_seg) ----------------
__global__ __launch_bounds__(192) void k_scan1(const float* __restrict__ delta,
    const float* __restrict__ xc, const float* __restrict__ Bm,
    const float* __restrict__ A_log, float* __restrict__ Ssg, float* __restrict__ Bsg){
  int b = blockIdx.x / NCc; int ci = blockIdx.x % NCc; int d = threadIdx.x;
  __shared__ float bm[CLc*NSTATE];
  for(int i=d;i<CLc*NSTATE;i+=192) bm[i]=Bm[(size_t)(b*Ln+ci*CLc)*NSTATE+i];
  float kA[NSTATE];
  { const float4* al=(const float4*)&A_log[d*NSTATE];
    #pragma unroll
    for(int v4=0;v4<4;v4++){ float4 a=al[v4];
      kA[v4*4+0]=-__expf(a.x)*1.4426950408889634f;
      kA[v4*4+1]=-__expf(a.y)*1.4426950408889634f;
      kA[v4*4+2]=-__expf(a.z)*1.4426950408889634f;
      kA[v4*4+3]=-__expf(a.w)*1.4426950408889634f; } }
  float h[NSTATE];
  #pragma unroll
  for(int n=0;n<NSTATE;n++) h[n]=0.f;
  float S=0.f;
  __syncthreads();
  const float* dp = delta + ((size_t)b*Ln+ci*CLc)*DIN + d;
  const float* xp = xc    + ((size_t)b*Ln+ci*CLc)*DIN + d;
  for(int ll=0;ll<CLc;ll++){
    float dl=dp[ll*DIN];
    float xv=xp[ll*DIN];
    float bx=dl*xv;
    S+=dl;
    float bv[NSTATE];
    { const float4* qq=(const float4*)&bm[ll*NSTATE];
      #pragma unroll
      for(int v4=0;v4<4;v4++){ float4 a=qq[v4]; bv[v4*4]=a.x; bv[v4*4+1]=a.y; bv[v4*4+2]=a.z; bv[v4*4+3]=a.w; } }
    #pragma unroll
    for(int n=0;n<NSTATE;n++){
      float a=exp2f(kA[n]*dl);
      h[n]=fmaf(a,h[n],bx*bv[n]);
    }
  }
  Ssg[(size_t)ci*(Bn*DIN) + b*DIN + d] = S;
  size_t wb = (((size_t)ci*Bn + b)*DIN + d)*NSTATE;
  #pragma unroll
  for(int v4=0;v4<4;v4++){
    float4 bv4;
    bv4.x=h[v4*4+0]; bv4.y=h[v4*4+1]; bv4.z=h[v4*4+2]; bv4.w=h[v4*4+3];
    *(float4*)&Bsg[wb+v4*4]=bv4;
  }
}

// ---------------- scan pass 2a: per-group aggregate (A_G, B_G) ----------------
// grid = Bn*(DIN/16)*NG = 384 blocks; 256 thr = 16 d x 16 n.
__global__ __launch_bounds__(256) void k_scan2a(const float* __restrict__ Ssg,
    const float* __restrict__ Bsg, const float* __restrict__ A_log,
    float* __restrict__ GA, float* __restrict__ GB){
  int t = threadIdx.x;
  int gi = blockIdx.x % NG;
  int rb = blockIdx.x / NG;
  int dg = rb % (DIN/16);
  int b  = rb / (DIN/16);
  int d = dg*16 + (t>>4);
  int n = t & 15;
  float kA = -__expf(A_log[d*NSTATE+n])*1.4426950408889634f;
  size_t off  = ((size_t)b*DIN + d)*NSTATE + n;
  size_t soff = (size_t)b*DIN + d;
  float h=0.f, Ap=1.f;
  for(int ci=gi*GC; ci<gi*GC+GC; ++ci){
    float a = exp2f(kA*Ssg[(size_t)ci*(Bn*DIN)+soff]);
    h = fmaf(a, h, Bsg[(size_t)ci*SLAB+off]);
    Ap *= a;
  }
  int lid = (int)off;
  GA[gi*SLAB+lid]=Ap; GB[gi*SLAB+lid]=h;
}

// ---------------- scan pass 2b: prefix over 16 groups per line ----------------
// grid = SLAB/256 = 24 blocks.
__global__ __launch_bounds__(256) void k_scan2b(const float* __restrict__ GA,
    const float* __restrict__ GB, float* __restrict__ GH){
  int lid = blockIdx.x*256 + threadIdx.x;
  float h=0.f;
  for(int gi=0; gi<NG; ++gi){
    GH[gi*SLAB+lid]=h;
    h = fmaf(GA[gi*SLAB+lid], h, GB[gi*SLAB+lid]);
  }
}

// ---------------- scan pass 2c: replay group, write h_in in place into Bsg ----------------
__global__ __launch_bounds__(256) void k_scan2c(const float* __restrict__ Ssg,
    float* __restrict__ Bsg, const float* __restrict__ A_log,
    const float* __restrict__ GH){
  int t = threadIdx.x;
  int gi = blockIdx.x % NG;
  int rb = blockIdx.x / NG;
  int dg = rb % (DIN/16);
  int b  = rb / (DIN/16);
  int d = dg*16 + (t>>4);
  int n = t & 15;
  float kA = -__expf(A_log[d*NSTATE+n])*1.4426950408889634f;
  size_t off  = ((size_t)b*DIN + d)*NSTATE + n;
  size_t soff = (size_t)b*DIN + d;
  int lid = (int)off;
  float h = GH[gi*SLAB+lid];
  for(int ci=gi*GC; ci<gi*GC+GC; ++ci){
    float a = exp2f(kA*Ssg[(size_t)ci*(Bn*DIN)+soff]);
    size_t idx = (size_t)ci*SLAB+off;
    float bb = Bsg[idx];
    Bsg[idx] = h;
    h = fmaf(a, h, bb);
  }
}

// ---------------- scan pass 3: replay from h_in, emit y*silu(z) ----------------
__global__ __launch_bounds__(192) void k_scan3(const float* __restrict__ delta,
    const float* __restrict__ xc, const float* __restrict__ Bm, const float* __restrict__ Cm,
    const float* __restrict__ Hseg, const float* __restrict__ A_log, const float* __restrict__ Dp,
    const float* __restrict__ zs, float* __restrict__ yacc, int dir){
  int b=blockIdx.x/NCc; int ci=blockIdx.x%NCc; int d=threadIdx.x;
  __shared__ float bm[CLc*NSTATE], cm[CLc*NSTATE];
  for(int i=d;i<CLc*NSTATE;i+=192){
    bm[i]=Bm[(size_t)(b*Ln+ci*CLc)*NSTATE+i];
    cm[i]=Cm[(size_t)(b*Ln+ci*CLc)*NSTATE+i];
  }
  float kA[NSTATE];
  { const float4* al=(const float4*)&A_log[d*NSTATE];
    #pragma unroll
    for(int v4=0;v4<4;v4++){ float4 a=al[v4];
      kA[v4*4+0]=-__expf(a.x)*1.4426950408889634f;
      kA[v4*4+1]=-__expf(a.y)*1.4426950408889634f;
      kA[v4*4+2]=-__expf(a.z)*1.4426950408889634f;
      kA[v4*4+3]=-__expf(a.w)*1.4426950408889634f; } }
  float Dd=Dp[d];
  float h[NSTATE];
  { size_t rb = (((size_t)ci*Bn + b)*DIN + d)*NSTATE;
    const float4* hp=(const float4*)&Hseg[rb];
    #pragma unroll
    for(int v4=0;v4<4;v4++){ float4 a=hp[v4]; h[v4*4]=a.x; h[v4*4+1]=a.y; h[v4*4+2]=a.z; h[v4*4+3]=a.w; } }
  __syncthreads();
  const float* dp = delta + ((size_t)b*Ln+ci*CLc)*DIN + d;
  const float* xp = xc    + ((size_t)b*Ln+ci*CLc)*DIN + d;
  const float* zp = zs    + ((size_t)b*Ln+ci*CLc)*DIN + d;
  for(int ll=0;ll<CLc;ll++){
    float dl=dp[ll*DIN];
    float xv=xp[ll*DIN];
    float zv=zp[ll*DIN];
    float bx=dl*xv;
    float bv[NSTATE], cv[NSTATE];
    { const float4* qq=(const float4*)&bm[ll*NSTATE];
      const float4* rr=(const float4*)&cm[ll*NSTATE];
      #pragma unroll
      for(int v4=0;v4<4;v4++){ float4 a=qq[v4]; bv[v4*4]=a.x; bv[v4*4+1]=a.y; bv[v4*4+2]=a.z; bv[v4*4+3]=a.w;
                               float4 c=rr[v4]; cv[v4*4]=c.x; cv[v4*4+1]=c.y; cv[v4*4+2]=c.z; cv[v4*4+3]=c.w; } }
    float y=0.f;
    #pragma unroll
    for(int n=0;n<NSTATE;n++){
      float a=exp2f(kA[n]*dl);
      h[n]=fmaf(a,h[n],bx*bv[n]);
      y=fmaf(h[n],cv[n],y);
    }
    y=fmaf(xv,Dd,y);
    float o=y*zv;
    int l=ci*CLc+ll;
    int p = dir? (Ln-1-l) : l;
    float* yp=&yacc[(size_t)(b*Ln+p)*DIN+d];
    if(dir==0) *yp=o; else *yp+=o;
  }
}

// ---------------- out-proj GEMM (192->96) + residual, write (B,C,L) ----------------
__global__ __launch_bounds__(256) void k_out(const float* __restrict__ x,
    const float* __restrict__ ya, const float* __restrict__ ow, float* __restrict__ out){
  __shared__ float yt[LT*196];
  int b=blockIdx.x/(Ln/LT); int l0=(blockIdx.x%(Ln/LT))*LT; int t=threadIdx.x;
  for(int i=t;i<LT*DIN;i+=256){ int j=i/DIN,c=i%DIN; yt[j*196+c]=ya[(size_t)(b*Ln+l0+j)*DIN+c]; }
  __syncthreads();
  int tp=t&15, tc=t>>4;
  float acc[6][4];
  #pragma unroll
  for(int j=0;j<6;j++)
    #pragma unroll
    for(int k=0;k<4;k++) acc[j][k]=0.f;
  for(int dd=0; dd<DIN; dd+=4){
    float4 yv[4];
    #pragma unroll
    for(int k=0;k<4;k++) yv[k]=*(const float4*)&yt[(tp+16*k)*196+dd];
    #pragma unroll
    for(int j=0;j<6;j++){
      float4 wv=*(const float4*)&ow[(tc+16*j)*DIN+dd];
      #pragma unroll
      for(int k=0;k<4;k++)
        acc[j][k]+=yv[k].x*wv.x+yv[k].y*wv.y+yv[k].z*wv.z+yv[k].w*wv.w;
    }
  }
  #pragma unroll
  for(int j=0;j<6;j++){ int c=tc+16*j;
    #pragma unroll
    for(int k=0;k<4;k++){ int p=l0+tp+16*k;
      int o=(b*CH+c)*Ln+p;
      out[o]=x[o]+acc[j][k]; } }
}

extern "C" void kernel_launch(void* const* d_in, const int* in_sizes, int n_in,
                              void* d_out, int out_size, void* d_ws, size_t ws_size,
                              hipStream_t stream){
  const float* x =(const float*)d_in[0];
  const float* g =(const float*)d_in[1];
  const float* be=(const float*)d_in[2];
  const float* ow=(const float*)d_in[3];
  const float* P[2][8];
  for(int dir=0;dir<2;dir++) for(int k=0;k<8;k++) P[dir][k]=(const float*)d_in[4+dir*8+k];
  float* ws=(float*)d_ws;
  size_t o=0;
  unsigned short* xnb = (unsigned short*)(ws+o); o+=(size_t)Bn*Ln*CH/2;
  unsigned short* wbf = (unsigned short*)(ws+o); o+=(size_t)(2*DIN*CH+2)/2;
  float* xi  = ws+o; o+=(size_t)Bn*Ln*DIN;   // hosts Bsg during scans (xi dead then)
  float* zsb = ws+o; o+=(size_t)Bn*Ln*DIN;
  float* xcb = ws+o; o+=(size_t)Bn*Ln*DIN;
  float* de  = ws+o; o+=(size_t)Bn*Ln*DIN;
  float* Bmb = ws+o; o+=(size_t)Bn*Ln*NSTATE;
  float* Cmb = ws+o; o+=(size_t)Bn*Ln*NSTATE;
  float* ya  = ws+o; o+=(size_t)Bn*Ln*DIN;
  float* Ssg = ws+o; o+=(size_t)NCc*Bn*DIN;
  float* GA  = ws+o; o+=(size_t)NG*SLAB;
  float* GB  = ws+o; o+=(size_t)NG*SLAB;
  float* GH  = ws+o; o+=(size_t)NG*SLAB;
  float* Bsg = xi;
  float* outp=(float*)d_out;

  k_ln<<<dim3(Bn*(Ln/LT)),dim3(256),0,stream>>>(x,g,be,xnb);
  for(int dir=0;dir<2;dir++){
    const float* in_w=P[dir][0]; const float* cw=P[dir][1]; const float* cb=P[dir][2];
    const float* xpw =P[dir][3]; const float* dtw=P[dir][4]; const float* dtb=P[dir][5];
    const float* Al  =P[dir][6]; const float* Dp =P[dir][7];
    k_wcast <<<dim3((2*DIN*CH+255)/256),dim3(256),0,stream>>>(in_w,wbf,2*DIN*CH);
    k_inproj<<<dim3(Bn*Ln/64),dim3(256),0,stream>>>(xnb,wbf,xi,zsb,dir);
    k_conv  <<<dim3((Bn*Ln*DIN+255)/256),dim3(256),0,stream>>>(xi,cw,cb,xcb);
    k_xproj <<<dim3(Bn*(Ln/LP)),dim3(256),0,stream>>>(xcb,xpw,dtw,dtb,de,Bmb,Cmb);
    k_scan1 <<<dim3(Bn*NCc),dim3(192),0,stream>>>(de,xcb,Bmb,Al,Ssg,Bsg);
    k_scan2a<<<dim3(Bn*(DIN/16)*NG),dim3(256),0,stream>>>(Ssg,Bsg,Al,GA,GB);
    k_scan2b<<<dim3(SLAB/256),dim3(256),0,stream>>>(GA,GB,GH);
    k_scan2c<<<dim3(Bn*(DIN/16)*NG),dim3(256),0,stream>>>(Ssg,Bsg,Al,GH);
    k_scan3 <<<dim3(Bn*NCc),dim3(192),0,stream>>>(de,xcb,Bmb,Cmb,Bsg,Al,Dp,zsb,ya,dir);
  }
  k_out<<<dim3(Bn*(Ln/LT)),dim3(256),0,stream>>>(x,ya,ow,outp);
}

// Round 6
// 390.470 us; speedup vs baseline: 1.7489x; 1.1592x over previous
//
#include <hip/hip_runtime.h>
#include <math.h>

#define CH 96
#define DIN 192
#define NSTATE 16
#define DTRc 6
#define NPROJ 38
#define Bn 2
#define Ln 16384
#define NCc 1024
#define CLc 16
#define SLAB (Bn*DIN*NSTATE)
#define NG 16
#define GC (NCc/NG)
#define LT 64

typedef __attribute__((ext_vector_type(8))) short bf16x8;
typedef __attribute__((ext_vector_type(4))) float f32x4;

__device__ __forceinline__ float sigf(float x){ return 1.f/(1.f+__expf(-x)); }
__device__ __forceinline__ unsigned short f2bf(float f){
  unsigned int u = __float_as_uint(f);
  unsigned int r = (u + 0x7fffu + ((u>>16)&1u)) >> 16;
  return (unsigned short)r;
}

// ---------------- LayerNorm: x (B,C,L) -> xn bf16 (B,L,C) ----------------
__global__ __launch_bounds__(256) void k_ln(const float* __restrict__ x,
    const float* __restrict__ g, const float* __restrict__ bb,
    unsigned short* __restrict__ xnb){
  __shared__ float tile[CH*65];
  __shared__ float ps[4*64], ps2[4*64];
  __shared__ float mus[64], rss[64];
  int b = blockIdx.x / (Ln/LT);
  int l0 = (blockIdx.x % (Ln/LT)) * LT;
  int t = threadIdx.x;
  for(int i=t;i<CH*LT;i+=256){ int c=i/LT, j=i%LT; tile[c*65+j] = x[(b*CH+c)*Ln + l0 + j]; }
  __syncthreads();
  { int j = t & 63, part = t >> 6;
    float s=0.f, s2=0.f;
    #pragma unroll
    for(int c=part*24; c<part*24+24; ++c){ float v=tile[c*65+j]; s+=v; s2+=v*v; }
    ps[part*64+j]=s; ps2[part*64+j]=s2; }
  __syncthreads();
  if(t<64){
    float s=0.f,s2=0.f;
    #pragma unroll
    for(int p=0;p<4;p++){ s+=ps[p*64+t]; s2+=ps2[p*64+t]; }
    float mu = s*(1.f/CH);
    float var = s2*(1.f/CH) - mu*mu;
    mus[t]=mu; rss[t]=rsqrtf(var+1e-5f);
  }
  __syncthreads();
  for(int i=t;i<CH*LT;i+=256){ int j=i/CH, c=i%CH;
    float v=(tile[c*65+j]-mus[j])*rss[j]*g[c]+bb[c];
    xnb[(size_t)(b*Ln+l0+j)*CH + c]=f2bf(v); }
}

// ---------------- weight casts ----------------
__global__ __launch_bounds__(256) void k_wcast(const float* __restrict__ w,
    unsigned short* __restrict__ wb, int n){
  int i = blockIdx.x*256 + threadIdx.x;
  if(i<n) wb[i]=f2bf(w[i]);
}
// xproj weights padded 38->48 rows
__global__ __launch_bounds__(256) void k_wcast_pad(const float* __restrict__ w,
    unsigned short* __restrict__ wb){
  int i = blockIdx.x*256 + threadIdx.x;
  if(i>=48*DIN) return;
  int r=i/DIN, c=i%DIN;
  wb[i] = (r<NPROJ) ? f2bf(w[r*DIN+c]) : 0;
}

// ---------------- In-proj via bf16 MFMA ----------------
__global__ __launch_bounds__(256) void k_inproj(const unsigned short* __restrict__ xnb,
    const unsigned short* __restrict__ wbf, float* __restrict__ xi,
    float* __restrict__ zs, int dir){
  int wave = threadIdx.x >> 6;
  int lane = threadIdx.x & 63;
  int row0 = blockIdx.x*64 + wave*16;
  int b  = row0 >> 14;
  int p0 = row0 & (Ln-1);
  int rlo = lane & 15, khi = lane >> 4;
  int p_in = dir ? (Ln-1-(p0+rlo)) : (p0+rlo);
  const bf16x8* Ap = (const bf16x8*)(xnb + ((size_t)b*Ln + p_in)*CH);
  bf16x8 a0 = Ap[khi];
  bf16x8 a1 = Ap[4+khi];
  bf16x8 a2 = Ap[8+khi];
  f32x4 acc[24];
  #pragma unroll
  for(int nt=0;nt<24;nt++){
    const bf16x8* Bp = (const bf16x8*)(wbf + (size_t)(nt*16+rlo)*CH);
    f32x4 c = {0.f,0.f,0.f,0.f};
    c = __builtin_amdgcn_mfma_f32_16x16x32_bf16(a0, Bp[khi],   c, 0,0,0);
    c = __builtin_amdgcn_mfma_f32_16x16x32_bf16(a1, Bp[4+khi], c, 0,0,0);
    c = __builtin_amdgcn_mfma_f32_16x16x32_bf16(a2, Bp[8+khi], c, 0,0,0);
    acc[nt]=c;
  }
  #pragma unroll
  for(int nt=0;nt<24;nt++){
    int n = nt*16 + rlo;
    #pragma unroll
    for(int j=0;j<4;j++){
      int p = p0 + khi*4 + j;
      size_t rowo = ((size_t)b*Ln + p)*DIN;
      float v = acc[nt][j];
      if(nt<12) xi[rowo + n] = v;
      else      zs[rowo + n - DIN] = v*sigf(v);
    }
  }
}

// ---------------- causal depthwise conv(4) + bias + silu, f32 + bf16 out ----------------
__global__ __launch_bounds__(256) void k_conv(const float* __restrict__ xi,
    const float* __restrict__ cw, const float* __restrict__ cb,
    float* __restrict__ xc, unsigned short* __restrict__ xch){
  int i = blockIdx.x*256 + threadIdx.x;
  if(i >= Bn*Ln*DIN) return;
  int d = i % DIN; int p = (i/DIN) % Ln; int b = i/(DIN*Ln);
  float acc = cb[d];
  #pragma unroll
  for(int k=0;k<4;k++){ int q = p-3+k; if(q>=0) acc += xi[(size_t)(b*Ln+q)*DIN+d]*cw[d*4+k]; }
  float v = acc * sigf(acc);
  xc[i] = v;
  xch[i] = f2bf(v);
}

// ---------------- x-proj via bf16 MFMA + delta softplus ----------------
// grid = Bn*Ln/64 blocks, 256 thr = 4 waves x 16 rows.
__global__ __launch_bounds__(256) void k_xproj(const unsigned short* __restrict__ xch,
    const unsigned short* __restrict__ wxp, const float* __restrict__ dtw,
    const float* __restrict__ dtb, float* __restrict__ delta,
    float* __restrict__ Bm, float* __restrict__ Cm){
  __shared__ float dbl[64*50];
  __shared__ float dtw_s[DIN*DTRc];
  int t = threadIdx.x;
  int wave = t>>6, lane = t&63;
  int rlo = lane&15, khi = lane>>4;
  int row0 = blockIdx.x*64 + wave*16;
  for(int i=t;i<DIN*DTRc;i+=256) dtw_s[i]=dtw[i];
  const bf16x8* Ap = (const bf16x8*)(xch + (size_t)(row0+rlo)*DIN);
  bf16x8 a[6];
  #pragma unroll
  for(int ks=0;ks<6;ks++) a[ks]=Ap[khi+4*ks];
  #pragma unroll
  for(int nt=0;nt<3;nt++){
    const bf16x8* Bp = (const bf16x8*)(wxp + (size_t)(nt*16+rlo)*DIN);
    f32x4 c = {0.f,0.f,0.f,0.f};
    #pragma unroll
    for(int ks=0;ks<6;ks++)
      c = __builtin_amdgcn_mfma_f32_16x16x32_bf16(a[ks], Bp[khi+4*ks], c, 0,0,0);
    #pragma unroll
    for(int j=0;j<4;j++)
      dbl[(wave*16+khi*4+j)*50 + nt*16+rlo] = c[j];
  }
  __syncthreads();
  int gr0 = blockIdx.x*64;
  for(int i=t;i<64*DIN;i+=256){
    int j=i/DIN, d=i%DIN;
    float aa=dtb[d];
    #pragma unroll
    for(int r=0;r<DTRc;r++) aa += dbl[j*50+r]*dtw_s[d*DTRc+r];
    float sp = fmaxf(aa,0.f) + __logf(1.f+__expf(-fabsf(aa)));
    delta[(size_t)(gr0+j)*DIN+d]=sp;
  }
  for(int i=t;i<64*32;i+=256){
    int j=i/32, q=i%32;
    float v=dbl[j*50+DTRc+q];
    if(q<NSTATE) Bm[(size_t)(gr0+j)*NSTATE+q]=v;
    else         Cm[(size_t)(gr0+j)*NSTATE+q-NSTATE]=v;
  }
}

// ---------------- scan pass 1: per-chunk (S=sum delta, B_seg) ----------------
__global__ __launch_bounds__(192) void k_scan1(const float* __restrict__ delta,
    const float* __restrict__ xc, const float* __restrict__ Bm,
    const float* __restrict__ A_log, float* __restrict__ Ssg, float* __restrict__ Bsg){
  int b = blockIdx.x / NCc; int ci = blockIdx.x % NCc; int d = threadIdx.x;
  __shared__ float bm[CLc*NSTATE];
  for(int i=d;i<CLc*NSTATE;i+=192) bm[i]=Bm[(size_t)(b*Ln+ci*CLc)*NSTATE+i];
  float kA[NSTATE];
  { const float4* al=(const float4*)&A_log[d*NSTATE];
    #pragma unroll
    for(int v4=0;v4<4;v4++){ float4 a=al[v4];
      kA[v4*4+0]=-__expf(a.x)*1.4426950408889634f;
      kA[v4*4+1]=-__expf(a.y)*1.4426950408889634f;
      kA[v4*4+2]=-__expf(a.z)*1.4426950408889634f;
      kA[v4*4+3]=-__expf(a.w)*1.4426950408889634f; } }
  float h[NSTATE];
  #pragma unroll
  for(int n=0;n<NSTATE;n++) h[n]=0.f;
  float S=0.f;
  __syncthreads();
  const float* dp = delta + ((size_t)b*Ln+ci*CLc)*DIN + d;
  const float* xp = xc    + ((size_t)b*Ln+ci*CLc)*DIN + d;
  for(int ll=0;ll<CLc;ll++){
    float dl=dp[ll*DIN];
    float xv=xp[ll*DIN];
    float bx=dl*xv;
    S+=dl;
    float bv[NSTATE];
    { const float4* qq=(const float4*)&bm[ll*NSTATE];
      #pragma unroll
      for(int v4=0;v4<4;v4++){ float4 a=qq[v4]; bv[v4*4]=a.x; bv[v4*4+1]=a.y; bv[v4*4+2]=a.z; bv[v4*4+3]=a.w; } }
    #pragma unroll
    for(int n=0;n<NSTATE;n++){
      float a=exp2f(kA[n]*dl);
      h[n]=fmaf(a,h[n],bx*bv[n]);
    }
  }
  Ssg[(size_t)ci*(Bn*DIN) + b*DIN + d] = S;
  size_t wb = (((size_t)ci*Bn + b)*DIN + d)*NSTATE;
  #pragma unroll
  for(int v4=0;v4<4;v4++){
    float4 bv4;
    bv4.x=h[v4*4+0]; bv4.y=h[v4*4+1]; bv4.z=h[v4*4+2]; bv4.w=h[v4*4+3];
    *(float4*)&Bsg[wb+v4*4]=bv4;
  }
}

// ---------------- scan pass 2a/2b/2c: parallel chunk combine ----------------
__global__ __launch_bounds__(256) void k_scan2a(const float* __restrict__ Ssg,
    const float* __restrict__ Bsg, const float* __restrict__ A_log,
    float* __restrict__ GA, float* __restrict__ GB){
  int t = threadIdx.x;
  int gi = blockIdx.x % NG;
  int rb = blockIdx.x / NG;
  int dg = rb % (DIN/16);
  int b  = rb / (DIN/16);
  int d = dg*16 + (t>>4);
  int n = t & 15;
  float kA = -__expf(A_log[d*NSTATE+n])*1.4426950408889634f;
  size_t off  = ((size_t)b*DIN + d)*NSTATE + n;
  size_t soff = (size_t)b*DIN + d;
  float h=0.f, Ap=1.f;
  for(int ci=gi*GC; ci<gi*GC+GC; ++ci){
    float a = exp2f(kA*Ssg[(size_t)ci*(Bn*DIN)+soff]);
    h = fmaf(a, h, Bsg[(size_t)ci*SLAB+off]);
    Ap *= a;
  }
  int lid = (int)off;
  GA[gi*SLAB+lid]=Ap; GB[gi*SLAB+lid]=h;
}

__global__ __launch_bounds__(256) void k_scan2b(const float* __restrict__ GA,
    const float* __restrict__ GB, float* __restrict__ GH){
  int lid = blockIdx.x*256 + threadIdx.x;
  float h=0.f;
  for(int gi=0; gi<NG; ++gi){
    GH[gi*SLAB+lid]=h;
    h = fmaf(GA[gi*SLAB+lid], h, GB[gi*SLAB+lid]);
  }
}

__global__ __launch_bounds__(256) void k_scan2c(const float* __restrict__ Ssg,
    float* __restrict__ Bsg, const float* __restrict__ A_log,
    const float* __restrict__ GH){
  int t = threadIdx.x;
  int gi = blockIdx.x % NG;
  int rb = blockIdx.x / NG;
  int dg = rb % (DIN/16);
  int b  = rb / (DIN/16);
  int d = dg*16 + (t>>4);
  int n = t & 15;
  float kA = -__expf(A_log[d*NSTATE+n])*1.4426950408889634f;
  size_t off  = ((size_t)b*DIN + d)*NSTATE + n;
  size_t soff = (size_t)b*DIN + d;
  int lid = (int)off;
  float h = GH[gi*SLAB+lid];
  for(int ci=gi*GC; ci<gi*GC+GC; ++ci){
    float a = exp2f(kA*Ssg[(size_t)ci*(Bn*DIN)+soff]);
    size_t idx = (size_t)ci*SLAB+off;
    float bb = Bsg[idx];
    Bsg[idx] = h;
    h = fmaf(a, h, bb);
  }
}

// ---------------- scan pass 3: replay, emit bf16 y*silu(z) per direction ----------------
__global__ __launch_bounds__(192) void k_scan3(const float* __restrict__ delta,
    const float* __restrict__ xc, const float* __restrict__ Bm, const float* __restrict__ Cm,
    const float* __restrict__ Hseg, const float* __restrict__ A_log, const float* __restrict__ Dp,
    const float* __restrict__ zs, unsigned short* __restrict__ yout, int dir){
  int b=blockIdx.x/NCc; int ci=blockIdx.x%NCc; int d=threadIdx.x;
  __shared__ float bm[CLc*NSTATE], cm[CLc*NSTATE];
  for(int i=d;i<CLc*NSTATE;i+=192){
    bm[i]=Bm[(size_t)(b*Ln+ci*CLc)*NSTATE+i];
    cm[i]=Cm[(size_t)(b*Ln+ci*CLc)*NSTATE+i];
  }
  float kA[NSTATE];
  { const float4* al=(const float4*)&A_log[d*NSTATE];
    #pragma unroll
    for(int v4=0;v4<4;v4++){ float4 a=al[v4];
      kA[v4*4+0]=-__expf(a.x)*1.4426950408889634f;
      kA[v4*4+1]=-__expf(a.y)*1.4426950408889634f;
      kA[v4*4+2]=-__expf(a.z)*1.4426950408889634f;
      kA[v4*4+3]=-__expf(a.w)*1.4426950408889634f; } }
  float Dd=Dp[d];
  float h[NSTATE];
  { size_t rb = (((size_t)ci*Bn + b)*DIN + d)*NSTATE;
    const float4* hp=(const float4*)&Hseg[rb];
    #pragma unroll
    for(int v4=0;v4<4;v4++){ float4 a=hp[v4]; h[v4*4]=a.x; h[v4*4+1]=a.y; h[v4*4+2]=a.z; h[v4*4+3]=a.w; } }
  __syncthreads();
  const float* dp = delta + ((size_t)b*Ln+ci*CLc)*DIN + d;
  const float* xp = xc    + ((size_t)b*Ln+ci*CLc)*DIN + d;
  const float* zp = zs    + ((size_t)b*Ln+ci*CLc)*DIN + d;
  for(int ll=0;ll<CLc;ll++){
    float dl=dp[ll*DIN];
    float xv=xp[ll*DIN];
    float zv=zp[ll*DIN];
    float bx=dl*xv;
    float bv[NSTATE], cv[NSTATE];
    { const float4* qq=(const float4*)&bm[ll*NSTATE];
      const float4* rr=(const float4*)&cm[ll*NSTATE];
      #pragma unroll
      for(int v4=0;v4<4;v4++){ float4 a=qq[v4]; bv[v4*4]=a.x; bv[v4*4+1]=a.y; bv[v4*4+2]=a.z; bv[v4*4+3]=a.w;
                               float4 c=rr[v4]; cv[v4*4]=c.x; cv[v4*4+1]=c.y; cv[v4*4+2]=c.z; cv[v4*4+3]=c.w; } }
    float y=0.f;
    #pragma unroll
    for(int n=0;n<NSTATE;n++){
      float a=exp2f(kA[n]*dl);
      h[n]=fmaf(a,h[n],bx*bv[n]);
      y=fmaf(h[n],cv[n],y);
    }
    y=fmaf(xv,Dd,y);
    float o=y*zv;
    int l=ci*CLc+ll;
    int p = dir? (Ln-1-l) : l;
    yout[(size_t)(b*Ln+p)*DIN+d]=f2bf(o);
  }
}

// ---------------- out-proj via bf16 MFMA + residual, write (B,C,L) ----------------
// grid = Bn*Ln/64, 256 thr = 4 waves x 16 rows; out = x + (yf+yb)@ow.T
__global__ __launch_bounds__(256) void k_out(const float* __restrict__ x,
    const unsigned short* __restrict__ yf, const unsigned short* __restrict__ yb,
    const unsigned short* __restrict__ owb, float* __restrict__ out){
  int t = threadIdx.x;
  int wave = t>>6, lane = t&63;
  int rlo = lane&15, khi = lane>>4;
  int row0 = blockIdx.x*64 + wave*16;
  int b  = row0 >> 14;
  int p0 = row0 & (Ln-1);
  const bf16x8* Af = (const bf16x8*)(yf + (size_t)(row0+rlo)*DIN);
  const bf16x8* Ab = (const bf16x8*)(yb + (size_t)(row0+rlo)*DIN);
  bf16x8 af[6], ab[6];
  #pragma unroll
  for(int ks=0;ks<6;ks++){ af[ks]=Af[khi+4*ks]; ab[ks]=Ab[khi+4*ks]; }
  #pragma unroll
  for(int nt=0;nt<6;nt++){
    const bf16x8* Bp = (const bf16x8*)(owb + (size_t)(nt*16+rlo)*DIN);
    f32x4 c = {0.f,0.f,0.f,0.f};
    #pragma unroll
    for(int ks=0;ks<6;ks++){
      bf16x8 bw = Bp[khi+4*ks];
      c = __builtin_amdgcn_mfma_f32_16x16x32_bf16(af[ks], bw, c, 0,0,0);
      c = __builtin_amdgcn_mfma_f32_16x16x32_bf16(ab[ks], bw, c, 0,0,0);
    }
    int cc = nt*16 + rlo;
    size_t o4 = (size_t)(b*CH+cc)*Ln + p0 + khi*4;
    float4 xv = *(const float4*)&x[o4];
    float4 r; r.x=xv.x+c[0]; r.y=xv.y+c[1]; r.z=xv.z+c[2]; r.w=xv.w+c[3];
    *(float4*)&out[o4] = r;
  }
}

extern "C" void kernel_launch(void* const* d_in, const int* in_sizes, int n_in,
                              void* d_out, int out_size, void* d_ws, size_t ws_size,
                              hipStream_t stream){
  const float* x =(const float*)d_in[0];
  const float* g =(const float*)d_in[1];
  const float* be=(const float*)d_in[2];
  const float* ow=(const float*)d_in[3];
  const float* P[2][8];
  for(int dir=0;dir<2;dir++) for(int k=0;k<8;k++) P[dir][k]=(const float*)d_in[4+dir*8+k];
  float* ws=(float*)d_ws;
  size_t o=0;
  unsigned short* xnb = (unsigned short*)(ws+o); o+=(size_t)Bn*Ln*CH/2;
  unsigned short* wbf = (unsigned short*)(ws+o); o+=(size_t)DIN*CH;        // 2*DIN*CH ushorts
  unsigned short* wxp = (unsigned short*)(ws+o); o+=(size_t)48*DIN/2;
  unsigned short* owb = (unsigned short*)(ws+o); o+=(size_t)CH*DIN/2;
  float* xi  = ws+o; o+=(size_t)Bn*Ln*DIN;   // hosts Bsg during scans
  float* zsb = ws+o; o+=(size_t)Bn*Ln*DIN;
  float* xcb = ws+o; o+=(size_t)Bn*Ln*DIN;
  unsigned short* xch = (unsigned short*)(ws+o); o+=(size_t)Bn*Ln*DIN/2;
  float* de  = ws+o; o+=(size_t)Bn*Ln*DIN;
  float* Bmb = ws+o; o+=(size_t)Bn*Ln*NSTATE;
  float* Cmb = ws+o; o+=(size_t)Bn*Ln*NSTATE;
  unsigned short* yf = (unsigned short*)(ws+o); o+=(size_t)Bn*Ln*DIN/2;
  unsigned short* yb = (unsigned short*)(ws+o); o+=(size_t)Bn*Ln*DIN/2;
  float* Ssg = ws+o; o+=(size_t)NCc*Bn*DIN;
  float* GA  = ws+o; o+=(size_t)NG*SLAB;
  float* GB  = ws+o; o+=(size_t)NG*SLAB;
  float* GH  = ws+o; o+=(size_t)NG*SLAB;
  float* Bsg = xi;
  float* outp=(float*)d_out;

  k_ln<<<dim3(Bn*(Ln/LT)),dim3(256),0,stream>>>(x,g,be,xnb);
  k_wcast<<<dim3((CH*DIN+255)/256),dim3(256),0,stream>>>(ow,owb,CH*DIN);
  for(int dir=0;dir<2;dir++){
    const float* in_w=P[dir][0]; const float* cw=P[dir][1]; const float* cb=P[dir][2];
    const float* xpw =P[dir][3]; const float* dtw=P[dir][4]; const float* dtb=P[dir][5];
    const float* Al  =P[dir][6]; const float* Dp =P[dir][7];
    k_wcast    <<<dim3((2*DIN*CH+255)/256),dim3(256),0,stream>>>(in_w,wbf,2*DIN*CH);
    k_wcast_pad<<<dim3((48*DIN+255)/256),dim3(256),0,stream>>>(xpw,wxp);
    k_inproj<<<dim3(Bn*Ln/64),dim3(256),0,stream>>>(xnb,wbf,xi,zsb,dir);
    k_conv  <<<dim3((Bn*Ln*DIN+255)/256),dim3(256),0,stream>>>(xi,cw,cb,xcb,xch);
    k_xproj <<<dim3(Bn*Ln/64),dim3(256),0,stream>>>(xch,wxp,dtw,dtb,de,Bmb,Cmb);
    k_scan1 <<<dim3(Bn*NCc),dim3(192),0,stream>>>(de,xcb,Bmb,Al,Ssg,Bsg);
    k_scan2a<<<dim3(Bn*(DIN/16)*NG),dim3(256),0,stream>>>(Ssg,Bsg,Al,GA,GB);
    k_scan2b<<<dim3(SLAB/256),dim3(256),0,stream>>>(GA,GB,GH);
    k_scan2c<<<dim3(Bn*(DIN/16)*NG),dim3(256),0,stream>>>(Ssg,Bsg,Al,GH);
    k_scan3 <<<dim3(Bn*NCc),dim3(192),0,stream>>>(de,xcb,Bmb,Cmb,Bsg,Al,Dp,zsb,(dir?yb:yf),dir);
  }
  k_out<<<dim3(Bn*Ln/64),dim3(256),0,stream>>>(x,yf,yb,owb,outp);
}

// Round 7
// 371.362 us; speedup vs baseline: 1.8389x; 1.0515x over previous
//
#include <hip/hip_runtime.h>
#include <math.h>

#define CH 96
#define DIN 192
#define NSTATE 16
#define DTRc 6
#define NPROJ 38
#define Bn 2
#define Ln 16384
#define NCc 1024
#define CLc 16
#define SLAB (Bn*DIN*NSTATE)
#define NG 16
#define GC (NCc/NG)
#define LT 64

typedef __attribute__((ext_vector_type(8))) short bf16x8;
typedef __attribute__((ext_vector_type(4))) float f32x4;
typedef unsigned short ushort_t;

__device__ __forceinline__ float sigf(float x){ return 1.f/(1.f+__expf(-x)); }
__device__ __forceinline__ unsigned short f2bf(float f){
  unsigned int u = __float_as_uint(f);
  unsigned int r = (u + 0x7fffu + ((u>>16)&1u)) >> 16;
  return (unsigned short)r;
}
__device__ __forceinline__ float bf2f(unsigned short u){
  return __uint_as_float(((unsigned int)u)<<16);
}

// ---------------- LayerNorm: x (B,C,L) -> xn bf16 (B,L,C) ----------------
__global__ __launch_bounds__(256) void k_ln(const float* __restrict__ x,
    const float* __restrict__ g, const float* __restrict__ bb,
    ushort_t* __restrict__ xnb){
  __shared__ float tile[CH*65];
  __shared__ float ps[4*64], ps2[4*64];
  __shared__ float mus[64], rss[64];
  int b = blockIdx.x / (Ln/LT);
  int l0 = (blockIdx.x % (Ln/LT)) * LT;
  int t = threadIdx.x;
  for(int i=t;i<CH*LT;i+=256){ int c=i/LT, j=i%LT; tile[c*65+j] = x[(b*CH+c)*Ln + l0 + j]; }
  __syncthreads();
  { int j = t & 63, part = t >> 6;
    float s=0.f, s2=0.f;
    #pragma unroll
    for(int c=part*24; c<part*24+24; ++c){ float v=tile[c*65+j]; s+=v; s2+=v*v; }
    ps[part*64+j]=s; ps2[part*64+j]=s2; }
  __syncthreads();
  if(t<64){
    float s=0.f,s2=0.f;
    #pragma unroll
    for(int p=0;p<4;p++){ s+=ps[p*64+t]; s2+=ps2[p*64+t]; }
    float mu = s*(1.f/CH);
    float var = s2*(1.f/CH) - mu*mu;
    mus[t]=mu; rss[t]=rsqrtf(var+1e-5f);
  }
  __syncthreads();
  for(int i=t;i<CH*LT;i+=256){ int j=i/CH, c=i%CH;
    float v=(tile[c*65+j]-mus[j])*rss[j]*g[c]+bb[c];
    xnb[(size_t)(b*Ln+l0+j)*CH + c]=f2bf(v); }
}

// ---------------- weight casts ----------------
__global__ __launch_bounds__(256) void k_wcast(const float* __restrict__ w,
    ushort_t* __restrict__ wb, int n){
  int i = blockIdx.x*256 + threadIdx.x;
  if(i<n) wb[i]=f2bf(w[i]);
}
// per-dir: in_w (2*DIN*CH) + xproj padded 38->48 rows
__global__ __launch_bounds__(256) void k_wcast_all(const float* __restrict__ in_w,
    const float* __restrict__ xpw, ushort_t* __restrict__ wbf, ushort_t* __restrict__ wxp){
  int i = blockIdx.x*256 + threadIdx.x;
  int n1 = 2*DIN*CH;
  if(i < n1){ wbf[i]=f2bf(in_w[i]); return; }
  int j = i - n1;
  if(j >= 48*DIN) return;
  int r=j/DIN, c=j%DIN;
  wxp[j] = (r<NPROJ) ? f2bf(xpw[r*DIN+c]) : 0;
}

// ---------------- fused in-proj MFMA + causal conv(4) + silu ----------------
// grid = Bn*Ln/64; 256 thr = 4 waves x 16 rows. Computes 64 xi rows + 16-row
// halo into LDS (bf16), z->zs global (bf16), then conv from LDS -> xch (bf16).
__global__ __launch_bounds__(256) void k_inprojconv(const ushort_t* __restrict__ xnb,
    const ushort_t* __restrict__ wbf, const float* __restrict__ cw,
    const float* __restrict__ cb, ushort_t* __restrict__ zs,
    ushort_t* __restrict__ xch, int dir){
  __shared__ ushort_t xis[80*196];
  int t = threadIdx.x;
  int wave = t>>6, lane = t&63;
  int rlo = lane&15, khi = lane>>4;
  int grow = blockIdx.x*64;            // linear row base in [0, Bn*Ln)
  int b  = grow >> 14;
  int p0 = grow & (Ln-1);
  // own-row A fragments
  int pr = p0 + wave*16 + rlo;
  int p_in = dir ? (Ln-1-pr) : pr;
  const bf16x8* Ap = (const bf16x8*)(xnb + ((size_t)b*Ln + p_in)*CH);
  bf16x8 a0=Ap[khi], a1=Ap[4+khi], a2=Ap[8+khi];
  // halo-row A fragments (rows p0-16..p0-1, clamped; unused values guarded in conv)
  int hr = p0 - 16 + rlo; if(hr<0) hr=0;
  int p_in_h = dir ? (Ln-1-hr) : hr;
  const bf16x8* Ah = (const bf16x8*)(xnb + ((size_t)b*Ln + p_in_h)*CH);
  bf16x8 h0=Ah[khi], h1=Ah[4+khi], h2=Ah[8+khi];

  #pragma unroll
  for(int nt=0;nt<24;nt++){
    const bf16x8* Bp = (const bf16x8*)(wbf + (size_t)(nt*16+rlo)*CH);
    f32x4 c = {0.f,0.f,0.f,0.f};
    c = __builtin_amdgcn_mfma_f32_16x16x32_bf16(a0, Bp[khi],   c, 0,0,0);
    c = __builtin_amdgcn_mfma_f32_16x16x32_bf16(a1, Bp[4+khi], c, 0,0,0);
    c = __builtin_amdgcn_mfma_f32_16x16x32_bf16(a2, Bp[8+khi], c, 0,0,0);
    if(nt<12){
      int col = nt*16 + rlo;
      #pragma unroll
      for(int j=0;j<4;j++){
        int lr = 16 + wave*16 + khi*4 + j;
        xis[lr*196 + col] = f2bf(c[j]);
      }
    } else {
      int n = nt*16 + rlo - DIN;
      #pragma unroll
      for(int j=0;j<4;j++){
        int gr = grow + wave*16 + khi*4 + j;
        float v = c[j];
        zs[(size_t)gr*DIN + n] = f2bf(v*sigf(v));
      }
    }
  }
  // halo xi tiles: wave w handles n-tiles 3w..3w+2
  #pragma unroll
  for(int m=0;m<3;m++){
    int nth = wave*3 + m;
    const bf16x8* Bp = (const bf16x8*)(wbf + (size_t)(nth*16+rlo)*CH);
    f32x4 c = {0.f,0.f,0.f,0.f};
    c = __builtin_amdgcn_mfma_f32_16x16x32_bf16(h0, Bp[khi],   c, 0,0,0);
    c = __builtin_amdgcn_mfma_f32_16x16x32_bf16(h1, Bp[4+khi], c, 0,0,0);
    c = __builtin_amdgcn_mfma_f32_16x16x32_bf16(h2, Bp[8+khi], c, 0,0,0);
    int col = nth*16 + rlo;
    #pragma unroll
    for(int j=0;j<4;j++){
      int lr = khi*4 + j;
      xis[lr*196 + col] = f2bf(c[j]);
    }
  }
  __syncthreads();
  // conv phase: 64*192 outputs, 48 per thread
  for(int k=0;k<48;k++){
    int idx = k*256 + t;
    int jloc = idx/DIN, d = idx%DIN;
    int pg = p0 + jloc;
    float acc = cb[d];
    #pragma unroll
    for(int kk=0;kk<4;kk++){
      int q = pg - 3 + kk;
      if(q>=0) acc += bf2f(xis[(13+jloc+kk)*196 + d]) * cw[d*4+kk];
    }
    float v = acc * sigf(acc);
    xch[(size_t)(grow+jloc)*DIN + d] = f2bf(v);
  }
}

// ---------------- x-proj via bf16 MFMA + delta softplus (bf16 outs) ----------------
__global__ __launch_bounds__(256) void k_xproj(const ushort_t* __restrict__ xch,
    const ushort_t* __restrict__ wxp, const float* __restrict__ dtw,
    const float* __restrict__ dtb, ushort_t* __restrict__ delta,
    ushort_t* __restrict__ Bm, ushort_t* __restrict__ Cm){
  __shared__ float dbl[64*50];
  __shared__ float dtw_s[DIN*DTRc];
  int t = threadIdx.x;
  int wave = t>>6, lane = t&63;
  int rlo = lane&15, khi = lane>>4;
  int row0 = blockIdx.x*64 + wave*16;
  for(int i=t;i<DIN*DTRc;i+=256) dtw_s[i]=dtw[i];
  const bf16x8* Ap = (const bf16x8*)(xch + (size_t)(row0+rlo)*DIN);
  bf16x8 a[6];
  #pragma unroll
  for(int ks=0;ks<6;ks++) a[ks]=Ap[khi+4*ks];
  #pragma unroll
  for(int nt=0;nt<3;nt++){
    const bf16x8* Bp = (const bf16x8*)(wxp + (size_t)(nt*16+rlo)*DIN);
    f32x4 c = {0.f,0.f,0.f,0.f};
    #pragma unroll
    for(int ks=0;ks<6;ks++)
      c = __builtin_amdgcn_mfma_f32_16x16x32_bf16(a[ks], Bp[khi+4*ks], c, 0,0,0);
    #pragma unroll
    for(int j=0;j<4;j++)
      dbl[(wave*16+khi*4+j)*50 + nt*16+rlo] = c[j];
  }
  __syncthreads();
  int gr0 = blockIdx.x*64;
  for(int i=t;i<64*DIN;i+=256){
    int j=i/DIN, d=i%DIN;
    float aa=dtb[d];
    #pragma unroll
    for(int r=0;r<DTRc;r++) aa += dbl[j*50+r]*dtw_s[d*DTRc+r];
    float sp = fmaxf(aa,0.f) + __logf(1.f+__expf(-fabsf(aa)));
    delta[(size_t)(gr0+j)*DIN+d]=f2bf(sp);
  }
  for(int i=t;i<64*32;i+=256){
    int j=i/32, q=i%32;
    float v=dbl[j*50+DTRc+q];
    if(q<NSTATE) Bm[(size_t)(gr0+j)*NSTATE+q]=f2bf(v);
    else         Cm[(size_t)(gr0+j)*NSTATE+q-NSTATE]=f2bf(v);
  }
}

// ---------------- scan pass 1: per-chunk (S=sum delta, B_seg) ----------------
__global__ __launch_bounds__(192) void k_scan1(const ushort_t* __restrict__ delta,
    const ushort_t* __restrict__ xc, const ushort_t* __restrict__ Bm,
    const float* __restrict__ A_log, float* __restrict__ Ssg, float* __restrict__ Bsg){
  int b = blockIdx.x / NCc; int ci = blockIdx.x % NCc; int d = threadIdx.x;
  __shared__ float bm[CLc*NSTATE];
  for(int i=d;i<CLc*NSTATE;i+=192) bm[i]=bf2f(Bm[(size_t)(b*Ln+ci*CLc)*NSTATE+i]);
  float kA[NSTATE];
  { const float4* al=(const float4*)&A_log[d*NSTATE];
    #pragma unroll
    for(int v4=0;v4<4;v4++){ float4 a=al[v4];
      kA[v4*4+0]=-__expf(a.x)*1.4426950408889634f;
      kA[v4*4+1]=-__expf(a.y)*1.4426950408889634f;
      kA[v4*4+2]=-__expf(a.z)*1.4426950408889634f;
      kA[v4*4+3]=-__expf(a.w)*1.4426950408889634f; } }
  float h[NSTATE];
  #pragma unroll
  for(int n=0;n<NSTATE;n++) h[n]=0.f;
  float S=0.f;
  __syncthreads();
  const ushort_t* dp = delta + ((size_t)b*Ln+ci*CLc)*DIN + d;
  const ushort_t* xp = xc    + ((size_t)b*Ln+ci*CLc)*DIN + d;
  for(int ll=0;ll<CLc;ll++){
    float dl=bf2f(dp[ll*DIN]);
    float xv=bf2f(xp[ll*DIN]);
    float bx=dl*xv;
    S+=dl;
    float bv[NSTATE];
    { const float4* qq=(const float4*)&bm[ll*NSTATE];
      #pragma unroll
      for(int v4=0;v4<4;v4++){ float4 a=qq[v4]; bv[v4*4]=a.x; bv[v4*4+1]=a.y; bv[v4*4+2]=a.z; bv[v4*4+3]=a.w; } }
    #pragma unroll
    for(int n=0;n<NSTATE;n++){
      float a=exp2f(kA[n]*dl);
      h[n]=fmaf(a,h[n],bx*bv[n]);
    }
  }
  Ssg[(size_t)ci*(Bn*DIN) + b*DIN + d] = S;
  size_t wb = (((size_t)ci*Bn + b)*DIN + d)*NSTATE;
  #pragma unroll
  for(int v4=0;v4<4;v4++){
    float4 bv4;
    bv4.x=h[v4*4+0]; bv4.y=h[v4*4+1]; bv4.z=h[v4*4+2]; bv4.w=h[v4*4+3];
    *(float4*)&Bsg[wb+v4*4]=bv4;
  }
}

// ---------------- scan pass 2a/2b/2c: parallel chunk combine ----------------
__global__ __launch_bounds__(256) void k_scan2a(const float* __restrict__ Ssg,
    const float* __restrict__ Bsg, const float* __restrict__ A_log,
    float* __restrict__ GA, float* __restrict__ GB){
  int t = threadIdx.x;
  int gi = blockIdx.x % NG;
  int rb = blockIdx.x / NG;
  int dg = rb % (DIN/16);
  int b  = rb / (DIN/16);
  int d = dg*16 + (t>>4);
  int n = t & 15;
  float kA = -__expf(A_log[d*NSTATE+n])*1.4426950408889634f;
  size_t off  = ((size_t)b*DIN + d)*NSTATE + n;
  size_t soff = (size_t)b*DIN + d;
  float h=0.f, Ap=1.f;
  for(int ci=gi*GC; ci<gi*GC+GC; ++ci){
    float a = exp2f(kA*Ssg[(size_t)ci*(Bn*DIN)+soff]);
    h = fmaf(a, h, Bsg[(size_t)ci*SLAB+off]);
    Ap *= a;
  }
  int lid = (int)off;
  GA[gi*SLAB+lid]=Ap; GB[gi*SLAB+lid]=h;
}

__global__ __launch_bounds__(256) void k_scan2b(const float* __restrict__ GA,
    const float* __restrict__ GB, float* __restrict__ GH){
  int lid = blockIdx.x*256 + threadIdx.x;
  float h=0.f;
  for(int gi=0; gi<NG; ++gi){
    GH[gi*SLAB+lid]=h;
    h = fmaf(GA[gi*SLAB+lid], h, GB[gi*SLAB+lid]);
  }
}

__global__ __launch_bounds__(256) void k_scan2c(const float* __restrict__ Ssg,
    float* __restrict__ Bsg, const float* __restrict__ A_log,
    const float* __restrict__ GH){
  int t = threadIdx.x;
  int gi = blockIdx.x % NG;
  int rb = blockIdx.x / NG;
  int dg = rb % (DIN/16);
  int b  = rb / (DIN/16);
  int d = dg*16 + (t>>4);
  int n = t & 15;
  float kA = -__expf(A_log[d*NSTATE+n])*1.4426950408889634f;
  size_t off  = ((size_t)b*DIN + d)*NSTATE + n;
  size_t soff = (size_t)b*DIN + d;
  int lid = (int)off;
  float h = GH[gi*SLAB+lid];
  for(int ci=gi*GC; ci<gi*GC+GC; ++ci){
    float a = exp2f(kA*Ssg[(size_t)ci*(Bn*DIN)+soff]);
    size_t idx = (size_t)ci*SLAB+off;
    float bb = Bsg[idx];
    Bsg[idx] = h;
    h = fmaf(a, h, bb);
  }
}

// ---------------- scan pass 3: replay, emit bf16 y*silu(z) per direction ----------------
__global__ __launch_bounds__(192) void k_scan3(const ushort_t* __restrict__ delta,
    const ushort_t* __restrict__ xc, const ushort_t* __restrict__ Bm, const ushort_t* __restrict__ Cm,
    const float* __restrict__ Hseg, const float* __restrict__ A_log, const float* __restrict__ Dp,
    const ushort_t* __restrict__ zs, ushort_t* __restrict__ yout, int dir){
  int b=blockIdx.x/NCc; int ci=blockIdx.x%NCc; int d=threadIdx.x;
  __shared__ float bm[CLc*NSTATE], cm[CLc*NSTATE];
  for(int i=d;i<CLc*NSTATE;i+=192){
    bm[i]=bf2f(Bm[(size_t)(b*Ln+ci*CLc)*NSTATE+i]);
    cm[i]=bf2f(Cm[(size_t)(b*Ln+ci*CLc)*NSTATE+i]);
  }
  float kA[NSTATE];
  { const float4* al=(const float4*)&A_log[d*NSTATE];
    #pragma unroll
    for(int v4=0;v4<4;v4++){ float4 a=al[v4];
      kA[v4*4+0]=-__expf(a.x)*1.4426950408889634f;
      kA[v4*4+1]=-__expf(a.y)*1.4426950408889634f;
      kA[v4*4+2]=-__expf(a.z)*1.4426950408889634f;
      kA[v4*4+3]=-__expf(a.w)*1.4426950408889634f; } }
  float Dd=Dp[d];
  float h[NSTATE];
  { size_t rb = (((size_t)ci*Bn + b)*DIN + d)*NSTATE;
    const float4* hp=(const float4*)&Hseg[rb];
    #pragma unroll
    for(int v4=0;v4<4;v4++){ float4 a=hp[v4]; h[v4*4]=a.x; h[v4*4+1]=a.y; h[v4*4+2]=a.z; h[v4*4+3]=a.w; } }
  __syncthreads();
  const ushort_t* dp = delta + ((size_t)b*Ln+ci*CLc)*DIN + d;
  const ushort_t* xp = xc    + ((size_t)b*Ln+ci*CLc)*DIN + d;
  const ushort_t* zp = zs    + ((size_t)b*Ln+ci*CLc)*DIN + d;
  for(int ll=0;ll<CLc;ll++){
    float dl=bf2f(dp[ll*DIN]);
    float xv=bf2f(xp[ll*DIN]);
    float zv=bf2f(zp[ll*DIN]);
    float bx=dl*xv;
    float bv[NSTATE], cv[NSTATE];
    { const float4* qq=(const float4*)&bm[ll*NSTATE];
      const float4* rr=(const float4*)&cm[ll*NSTATE];
      #pragma unroll
      for(int v4=0;v4<4;v4++){ float4 a=qq[v4]; bv[v4*4]=a.x; bv[v4*4+1]=a.y; bv[v4*4+2]=a.z; bv[v4*4+3]=a.w;
                               float4 c=rr[v4]; cv[v4*4]=c.x; cv[v4*4+1]=c.y; cv[v4*4+2]=c.z; cv[v4*4+3]=c.w; } }
    float y=0.f;
    #pragma unroll
    for(int n=0;n<NSTATE;n++){
      float a=exp2f(kA[n]*dl);
      h[n]=fmaf(a,h[n],bx*bv[n]);
      y=fmaf(h[n],cv[n],y);
    }
    y=fmaf(xv,Dd,y);
    float o=y*zv;
    int l=ci*CLc+ll;
    int p = dir? (Ln-1-l) : l;
    yout[(size_t)(b*Ln+p)*DIN+d]=f2bf(o);
  }
}

// ---------------- out-proj via bf16 MFMA + residual, write (B,C,L) ----------------
__global__ __launch_bounds__(256) void k_out(const float* __restrict__ x,
    const ushort_t* __restrict__ yf, const ushort_t* __restrict__ yb,
    const ushort_t* __restrict__ owb, float* __restrict__ out){
  int t = threadIdx.x;
  int wave = t>>6, lane = t&63;
  int rlo = lane&15, khi = lane>>4;
  int row0 = blockIdx.x*64 + wave*16;
  int b  = row0 >> 14;
  int p0 = row0 & (Ln-1);
  const bf16x8* Af = (const bf16x8*)(yf + (size_t)(row0+rlo)*DIN);
  const bf16x8* Ab = (const bf16x8*)(yb + (size_t)(row0+rlo)*DIN);
  bf16x8 af[6], ab[6];
  #pragma unroll
  for(int ks=0;ks<6;ks++){ af[ks]=Af[khi+4*ks]; ab[ks]=Ab[khi+4*ks]; }
  #pragma unroll
  for(int nt=0;nt<6;nt++){
    const bf16x8* Bp = (const bf16x8*)(owb + (size_t)(nt*16+rlo)*DIN);
    f32x4 c = {0.f,0.f,0.f,0.f};
    #pragma unroll
    for(int ks=0;ks<6;ks++){
      bf16x8 bw = Bp[khi+4*ks];
      c = __builtin_amdgcn_mfma_f32_16x16x32_bf16(af[ks], bw, c, 0,0,0);
      c = __builtin_amdgcn_mfma_f32_16x16x32_bf16(ab[ks], bw, c, 0,0,0);
    }
    int cc = nt*16 + rlo;
    size_t o4 = (size_t)(b*CH+cc)*Ln + p0 + khi*4;
    float4 xv = *(const float4*)&x[o4];
    float4 r; r.x=xv.x+c[0]; r.y=xv.y+c[1]; r.z=xv.z+c[2]; r.w=xv.w+c[3];
    *(float4*)&out[o4] = r;
  }
}

extern "C" void kernel_launch(void* const* d_in, const int* in_sizes, int n_in,
                              void* d_out, int out_size, void* d_ws, size_t ws_size,
                              hipStream_t stream){
  const float* x =(const float*)d_in[0];
  const float* g =(const float*)d_in[1];
  const float* be=(const float*)d_in[2];
  const float* ow=(const float*)d_in[3];
  const float* P[2][8];
  for(int dir=0;dir<2;dir++) for(int k=0;k<8;k++) P[dir][k]=(const float*)d_in[4+dir*8+k];
  float* ws=(float*)d_ws;
  size_t o=0;
  ushort_t* xnb = (ushort_t*)(ws+o); o+=(size_t)Bn*Ln*CH/2;
  ushort_t* wbf = (ushort_t*)(ws+o); o+=(size_t)DIN*CH;       // 2*DIN*CH bf16
  ushort_t* wxp = (ushort_t*)(ws+o); o+=(size_t)48*DIN/2;
  ushort_t* owb = (ushort_t*)(ws+o); o+=(size_t)CH*DIN/2;
  ushort_t* zsb = (ushort_t*)(ws+o); o+=(size_t)Bn*Ln*DIN/2;
  ushort_t* xch = (ushort_t*)(ws+o); o+=(size_t)Bn*Ln*DIN/2;
  ushort_t* deb = (ushort_t*)(ws+o); o+=(size_t)Bn*Ln*DIN/2;
  ushort_t* Bmb = (ushort_t*)(ws+o); o+=(size_t)Bn*Ln*NSTATE/2;
  ushort_t* Cmb = (ushort_t*)(ws+o); o+=(size_t)Bn*Ln*NSTATE/2;
  ushort_t* yf  = (ushort_t*)(ws+o); o+=(size_t)Bn*Ln*DIN/2;
  ushort_t* yb  = (ushort_t*)(ws+o); o+=(size_t)Bn*Ln*DIN/2;
  float* Ssg = ws+o; o+=(size_t)NCc*Bn*DIN;
  float* Bsg = ws+o; o+=(size_t)SLAB*NCc;
  float* GA  = ws+o; o+=(size_t)NG*SLAB;
  float* GB  = ws+o; o+=(size_t)NG*SLAB;
  float* GH  = ws+o; o+=(size_t)NG*SLAB;
  float* outp=(float*)d_out;

  k_ln<<<dim3(Bn*(Ln/LT)),dim3(256),0,stream>>>(x,g,be,xnb);
  k_wcast<<<dim3((CH*DIN+255)/256),dim3(256),0,stream>>>(ow,owb,CH*DIN);
  for(int dir=0;dir<2;dir++){
    const float* in_w=P[dir][0]; const float* cw=P[dir][1]; const float* cb=P[dir][2];
    const float* xpw =P[dir][3]; const float* dtw=P[dir][4]; const float* dtb=P[dir][5];
    const float* Al  =P[dir][6]; const float* Dp =P[dir][7];
    k_wcast_all<<<dim3((2*DIN*CH+48*DIN+255)/256),dim3(256),0,stream>>>(in_w,xpw,wbf,wxp);
    k_inprojconv<<<dim3(Bn*Ln/64),dim3(256),0,stream>>>(xnb,wbf,cw,cb,zsb,xch,dir);
    k_xproj <<<dim3(Bn*Ln/64),dim3(256),0,stream>>>(xch,wxp,dtw,dtb,deb,Bmb,Cmb);
    k_scan1 <<<dim3(Bn*NCc),dim3(192),0,stream>>>(deb,xch,Bmb,Al,Ssg,Bsg);
    k_scan2a<<<dim3(Bn*(DIN/16)*NG),dim3(256),0,stream>>>(Ssg,Bsg,Al,GA,GB);
    k_scan2b<<<dim3(SLAB/256),dim3(256),0,stream>>>(GA,GB,GH);
    k_scan2c<<<dim3(Bn*(DIN/16)*NG),dim3(256),0,stream>>>(Ssg,Bsg,Al,GH);
    k_scan3 <<<dim3(Bn*NCc),dim3(192),0,stream>>>(deb,xch,Bmb,Cmb,Bsg,Al,Dp,zsb,(dir?yb:yf),dir);
  }
  k_out<<<dim3(Bn*Ln/64),dim3(256),0,stream>>>(x,yf,yb,owb,outp);
}